// Round 1
// baseline (79.079 us; speedup 1.0000x reference)
//
#include <hip/hip_runtime.h>

// DMLoss: chamfer-style polygon offset loss.
// N=256 batches, P=128 points, TIME=10 interpolation steps.
// Strategy: one block per batch (256 blocks = 1 per CU), 256 threads.
// Targets (1280 x float2) staged in LDS; argmin scans use LDS broadcast reads.
// Thread tid: point i = tid & 127, half = tid >> 7 splits the scan range.
// Strict '<' updates + "lower half wins ties" preserve jnp.argmin first-occurrence.

constexpr int N_  = 256;
constexpr int P_  = 128;
constexpr int T_  = 10;
constexpr int PT_ = P_ * T_;   // 1280

__device__ __forceinline__ float smooth_l1(float diff) {
  // BETA = 0.25: diff<beta ? 0.5*d*d/beta : d - beta/2
  float a = fabsf(diff);
  return (a < 0.25f) ? (2.0f * a * a) : (a - 0.125f);
}

__global__ __launch_bounds__(256) void dm_partial_kernel(
    const float* __restrict__ pred_c, const float* __restrict__ pred_o,
    const float* __restrict__ gt_c,  const float* __restrict__ gt_k,
    const int* __restrict__ mask, float4* __restrict__ partial)
{
  const int n    = blockIdx.x;
  const int tid  = threadIdx.x;      // 0..255
  const int i    = tid & (P_ - 1);   // owned point index
  const int half = tid >> 7;         // 0 or 1: which half of the scan range

  __shared__ float2 tg[PT_];   // interpolated targets (10 KB)
  __shared__ float2 pc[P_];    // pred_contours[n]
  __shared__ float2 po[P_];    // pred_offsets[n]
  __shared__ float2 gc[P_];    // gt_contours[n]
  __shared__ float  bd[P_];    // best-dist combine buffer
  __shared__ int    bi[P_];    // best-idx combine buffer
  __shared__ float4 redv[4];   // cross-wave reduction

  const float2* pc_g = (const float2*)pred_c + n * P_;
  const float2* po_g = (const float2*)pred_o + n * P_;
  const float2* gc_g = (const float2*)gt_c  + n * P_;
  const float2* gk_g = (const float2*)gt_k  + n * P_;

  if (tid < P_) {
    pc[tid] = pc_g[tid];
    po[tid] = po_g[tid];
    gc[tid] = gc_g[tid];
  }
  __syncthreads();

  // ---- build interpolated targets: tg[p*10+t] = gt[p]*s + gt[p-1]*(1-s), s=t/10
  for (int j = tid; j < PT_; j += 256) {
    int p = j / T_;
    int t = j - p * T_;
    float s  = (float)t / 10.0f;     // match f32 division rounding of reference
    float ns = 1.0f - s;
    float2 a = gc[p];
    float2 b = gc[(p + P_ - 1) & (P_ - 1)];   // roll by +1 => neighbor p-1
    float2 v;
    v.x = a.x * s + b.x * ns;
    v.y = a.y * s + b.y * ns;
    tg[j] = v;
  }
  __syncthreads();

  // ---- item 1: pred point i vs all 1280 targets (each half scans 640) ----
  const float2 p = pc[i];
  float best = 3.0e38f; int bestj = 0;
  {
    const int j0 = half * (PT_ / 2);
    for (int j = j0; j < j0 + PT_ / 2; ++j) {
      float2 t = tg[j];                        // LDS broadcast (same j all lanes)
      float dx = p.x - t.x, dy = p.y - t.y;
      float d = dx * dx + dy * dy;
      if (d < best) { best = d; bestj = j; }   // strict < => first occurrence
    }
  }
  if (half == 0) { bd[i] = best; bi[i] = bestj; }
  __syncthreads();
  if (half == 1 && best < bd[i]) { bd[i] = best; bi[i] = bestj; }  // ties -> lower j
  __syncthreads();

  float s1 = 0.0f, c1 = 0.0f;
  if (half == 0) {
    float d = bd[i];
    if (d <= 1.0e6f) {                         // BOUND2
      float2 t = tg[bi[i]];
      float2 o = po[i];
      float tx = (t.x - p.x) * 0.25f;          // / STRIDE
      float ty = (t.y - p.y) * 0.25f;
      s1 = smooth_l1(o.x - tx) + smooth_l1(o.y - ty);
      c1 = 1.0f;
    }
  }
  __syncthreads();   // bd/bi about to be reused

  // ---- item 2: gt key point i vs all 128 pred points (each half scans 64) ----
  const float2 k = gk_g[i];
  float best2 = 3.0e38f; int bestj2 = 0;
  {
    const int j0 = half * (P_ / 2);
    for (int j = j0; j < j0 + P_ / 2; ++j) {
      float2 q = pc[j];
      float dx = k.x - q.x, dy = k.y - q.y;
      float d = dx * dx + dy * dy;
      if (d < best2) { best2 = d; bestj2 = j; }
    }
  }
  if (half == 0) { bd[i] = best2; bi[i] = bestj2; }
  __syncthreads();
  if (half == 1 && best2 < bd[i]) { bd[i] = best2; bi[i] = bestj2; }
  __syncthreads();

  float s2 = 0.0f, c2 = 0.0f;
  if (half == 0) {
    float d = bd[i];
    if (d <= 1.0e6f && mask[n * P_ + i] != 0) {
      int j = bi[i];
      float2 q = pc[j];
      float2 o = po[j];
      float tx = (k.x - q.x) * 0.25f;
      float ty = (k.y - q.y) * 0.25f;
      s2 = smooth_l1(o.x - tx) + smooth_l1(o.y - ty);
      c2 = 1.0f;
    }
  }

  // ---- block reduction of (s1,c1,s2,c2) over 256 threads ----
  #pragma unroll
  for (int off = 32; off > 0; off >>= 1) {
    s1 += __shfl_down(s1, off);
    c1 += __shfl_down(c1, off);
    s2 += __shfl_down(s2, off);
    c2 += __shfl_down(c2, off);
  }
  const int wave = tid >> 6;
  const int lane = tid & 63;
  if (lane == 0) redv[wave] = make_float4(s1, c1, s2, c2);
  __syncthreads();
  if (tid == 0) {
    float4 r = redv[0];
    #pragma unroll
    for (int w = 1; w < 4; ++w) {
      float4 q = redv[w];
      r.x += q.x; r.y += q.y; r.z += q.z; r.w += q.w;
    }
    partial[n] = r;
  }
}

__global__ __launch_bounds__(256) void dm_final_kernel(
    const float4* __restrict__ partial, float* __restrict__ out)
{
  const int tid = threadIdx.x;     // 256 threads, one per batch
  float4 v = partial[tid];
  float s1 = v.x, c1 = v.y, s2 = v.z, c2 = v.w;
  #pragma unroll
  for (int off = 32; off > 0; off >>= 1) {
    s1 += __shfl_down(s1, off);
    c1 += __shfl_down(c1, off);
    s2 += __shfl_down(s2, off);
    c2 += __shfl_down(c2, off);
  }
  __shared__ float4 redv[4];
  const int wave = tid >> 6;
  const int lane = tid & 63;
  if (lane == 0) redv[wave] = make_float4(s1, c1, s2, c2);
  __syncthreads();
  if (tid == 0) {
    float4 r = redv[0];
    #pragma unroll
    for (int w = 1; w < 4; ++w) {
      float4 q = redv[w];
      r.x += q.x; r.y += q.y; r.z += q.z; r.w += q.w;
    }
    // masked means: sum / max(2*count, 1), each weighted by 0.5 (KEY_W)
    float l1 = (r.x / fmaxf(r.y * 2.0f, 1.0f)) * 0.5f;
    float l2 = (r.z / fmaxf(r.w * 2.0f, 1.0f)) * 0.5f;
    out[0] = l1 + l2;
  }
}

extern "C" void kernel_launch(void* const* d_in, const int* in_sizes, int n_in,
                              void* d_out, int out_size, void* d_ws, size_t ws_size,
                              hipStream_t stream) {
  const float* pred_c = (const float*)d_in[0];   // pred_contours (256,128,2)
  const float* pred_o = (const float*)d_in[1];   // pred_offsets  (256,128,2)
  const float* gt_c   = (const float*)d_in[2];   // gt_contours   (256,128,2)
  const float* gt_k   = (const float*)d_in[3];   // gt_key_points (256,128,2)
  const int*   mask   = (const int*)d_in[4];     // gt_key_points_mask (256,128)
  float4* partial = (float4*)d_ws;               // 256 * 16 B = 4 KB scratch

  dm_partial_kernel<<<N_, 256, 0, stream>>>(pred_c, pred_o, gt_c, gt_k, mask, partial);
  dm_final_kernel<<<1, 256, 0, stream>>>(partial, (float*)d_out);
}

// Round 2
// 70.181 us; speedup vs baseline: 1.1268x; 1.1268x over previous
//
#include <hip/hip_runtime.h>

// DMLoss: chamfer-style polygon offset loss. N=256, P=128, TIME=10.
//
// R2 strategy: one block per batch (256 blocks, 1/CU), 1024 threads (16 waves
// -> 4 waves/SIMD for latency hiding; R1's 256-thread version was
// LDS-latency-bound at 1 wave/SIMD with a rolled 640-iter dependent scan).
//
// Item 1 is computed analytically per segment instead of scanning 10 samples:
// the 10 interpolated points of segment p lie on v(s) = a*s + b*(1-s),
// s = t/10. d^2(s) is a convex quadratic; the discrete argmin over t in [0,9]
// is one of {floor(10*s_vertex), +1} (clamped). We evaluate those two
// candidates with REFERENCE-style arithmetic (s from a t/10.0f table, mul-add
// form) so cross-segment argmin comparisons match the reference's values.
// Tie-breaks preserve jnp.argmin first-occurrence: lower t within a segment,
// chunks scanned in ascending p, chunk results combined in ascending order.

constexpr int N_ = 256;
constexpr int P_ = 128;

__device__ __forceinline__ float smooth_l1(float diff) {
  // BETA = 0.25: d<beta ? 0.5*d*d/beta : d - beta/2
  float a = fabsf(diff);
  return (a < 0.25f) ? (2.0f * a * a) : (a - 0.125f);
}

__global__ __launch_bounds__(1024) void dm_partial_kernel(
    const float* __restrict__ pred_c, const float* __restrict__ pred_o,
    const float* __restrict__ gt_c,  const float* __restrict__ gt_k,
    const int* __restrict__ mask, float4* __restrict__ partial)
{
  const int n   = blockIdx.x;
  const int tid = threadIdx.x;       // 0..1023
  const int i   = tid & (P_ - 1);    // owned point / key index
  const int q   = tid >> 7;          // 0..7: which chunk of 16 segments/preds

  __shared__ float2 pc[P_];          // pred_contours[n]
  __shared__ float2 po[P_];          // pred_offsets[n]
  __shared__ float4 segA[P_];        // (a.x, a.y, b.x, b.y) ; a=gt[p], b=gt[p-1]
  __shared__ float2 segE[P_];        // e = a - b
  __shared__ float  segI[P_];        // 1 / |e|^2
  __shared__ float  st[12];          // s = t / 10.0f, t = 0..9 (+pad)
  __shared__ float  bd[8][P_];       // per-chunk best dist
  __shared__ int    bj[8][P_];       // per-chunk best index
  __shared__ float4 redw[16];        // cross-wave reduction

  const float2* pc_g = (const float2*)pred_c + n * P_;
  const float2* po_g = (const float2*)pred_o + n * P_;
  const float2* gc_g = (const float2*)gt_c  + n * P_;
  const float2* gk_g = (const float2*)gt_k  + n * P_;

  if (tid < P_) {
    int p = tid;
    float2 a = gc_g[p];
    float2 b = gc_g[(p + P_ - 1) & (P_ - 1)];
    segA[p] = make_float4(a.x, a.y, b.x, b.y);
    float ex = a.x - b.x, ey = a.y - b.y;
    segE[p] = make_float2(ex, ey);
    float e2 = ex * ex + ey * ey;
    segI[p] = (e2 > 0.0f) ? (1.0f / e2) : 0.0f;
  } else if (tid < 2 * P_) {
    pc[tid - P_] = pc_g[tid - P_];
  } else if (tid < 3 * P_) {
    po[tid - 2 * P_] = po_g[tid - 2 * P_];
  } else if (tid < 3 * P_ + 10) {
    int t = tid - 3 * P_;
    st[t] = (float)t / 10.0f;        // match reference f32 division rounding
  }
  __syncthreads();

  // ================= item 1: pred point i vs 128 segments =================
  const float2 pt = pc[i];
  float best = 3.0e38f; int bestj = 0;
  {
    const int p0 = q * 16;
    #pragma unroll 4
    for (int p = p0; p < p0 + 16; ++p) {
      float4 ab  = segA[p];          // broadcast reads (uniform p per wave)
      float2 e   = segE[p];
      float  inv = segI[p];
      float fx = ab.z - pt.x, fy = ab.w - pt.y;     // f = b - point
      float ef = e.x * fx + e.y * fy;
      float tf = -(ef * inv) * 10.0f;               // vertex in t-units
      int tl = (int)floorf(tf);
      tl = min(max(tl, 0), 8);
      float s0 = st[tl], s1v = st[tl + 1];
      float ns0 = 1.0f - s0, ns1 = 1.0f - s1v;
      float v0x = ab.x * s0 + ab.z * ns0;
      float v0y = ab.y * s0 + ab.w * ns0;
      float v1x = ab.x * s1v + ab.z * ns1;
      float v1y = ab.y * s1v + ab.w * ns1;
      float dx0 = pt.x - v0x, dy0 = pt.y - v0y;
      float dx1 = pt.x - v1x, dy1 = pt.y - v1y;
      float d0 = dx0 * dx0 + dy0 * dy0;
      float d1 = dx1 * dx1 + dy1 * dy1;
      bool c  = d1 < d0;                            // tie -> lower t
      float dl = c ? d1 : d0;
      int   jl = p * 10 + (c ? tl + 1 : tl);
      if (dl < best) { best = dl; bestj = jl; }     // strict < => first occur.
    }
  }
  bd[q][i] = best; bj[q][i] = bestj;
  __syncthreads();

  float s1 = 0.0f, c1 = 0.0f;
  if (q == 0) {
    float bb = bd[0][i]; int jj = bj[0][i];
    #pragma unroll
    for (int w = 1; w < 8; ++w) {
      float d = bd[w][i];
      if (d < bb) { bb = d; jj = bj[w][i]; }        // ascending q => lower j wins ties
    }
    if (bb <= 1.0e6f) {                             // BOUND2
      int p = jj / 10, t = jj - (jj / 10) * 10;
      float4 ab = segA[p];
      float s  = st[t], ns = 1.0f - s;
      float vx = ab.x * s + ab.z * ns;
      float vy = ab.y * s + ab.w * ns;
      float2 o = po[i];
      float tx = (vx - pt.x) * 0.25f;               // / STRIDE
      float ty = (vy - pt.y) * 0.25f;
      s1 = smooth_l1(o.x - tx) + smooth_l1(o.y - ty);
      c1 = 1.0f;
    }
  }
  __syncthreads();   // bd/bj about to be reused

  // ================= item 2: key point i vs 128 pred points ================
  const float2 k = gk_g[i];
  float best2 = 3.0e38f; int bestj2 = 0;
  {
    const int j0 = q * 16;
    #pragma unroll 4
    for (int j = j0; j < j0 + 16; ++j) {
      float2 pp = pc[j];
      float dx = k.x - pp.x, dy = k.y - pp.y;
      float d = dx * dx + dy * dy;
      if (d < best2) { best2 = d; bestj2 = j; }
    }
  }
  bd[q][i] = best2; bj[q][i] = bestj2;
  __syncthreads();

  float s2 = 0.0f, c2 = 0.0f;
  if (q == 0) {
    float bb = bd[0][i]; int jj = bj[0][i];
    #pragma unroll
    for (int w = 1; w < 8; ++w) {
      float d = bd[w][i];
      if (d < bb) { bb = d; jj = bj[w][i]; }
    }
    if (bb <= 1.0e6f && mask[n * P_ + i] != 0) {
      float2 pp = pc[jj];
      float2 o  = po[jj];
      float tx = (k.x - pp.x) * 0.25f;
      float ty = (k.y - pp.y) * 0.25f;
      s2 = smooth_l1(o.x - tx) + smooth_l1(o.y - ty);
      c2 = 1.0f;
    }
  }

  // ---- block reduction of (s1,c1,s2,c2) over 16 waves ----
  #pragma unroll
  for (int off = 32; off > 0; off >>= 1) {
    s1 += __shfl_down(s1, off);
    c1 += __shfl_down(c1, off);
    s2 += __shfl_down(s2, off);
    c2 += __shfl_down(c2, off);
  }
  const int wave = tid >> 6;
  const int lane = tid & 63;
  if (lane == 0) redw[wave] = make_float4(s1, c1, s2, c2);
  __syncthreads();
  if (tid == 0) {
    float4 r = redw[0];
    #pragma unroll
    for (int w = 1; w < 16; ++w) {
      float4 v = redw[w];
      r.x += v.x; r.y += v.y; r.z += v.z; r.w += v.w;
    }
    partial[n] = r;
  }
}

__global__ __launch_bounds__(256) void dm_final_kernel(
    const float4* __restrict__ partial, float* __restrict__ out)
{
  const int tid = threadIdx.x;     // 256 threads, one per batch
  float4 v = partial[tid];
  float s1 = v.x, c1 = v.y, s2 = v.z, c2 = v.w;
  #pragma unroll
  for (int off = 32; off > 0; off >>= 1) {
    s1 += __shfl_down(s1, off);
    c1 += __shfl_down(c1, off);
    s2 += __shfl_down(s2, off);
    c2 += __shfl_down(c2, off);
  }
  __shared__ float4 redv[4];
  const int wave = tid >> 6;
  const int lane = tid & 63;
  if (lane == 0) redv[wave] = make_float4(s1, c1, s2, c2);
  __syncthreads();
  if (tid == 0) {
    float4 r = redv[0];
    #pragma unroll
    for (int w = 1; w < 4; ++w) {
      float4 q = redv[w];
      r.x += q.x; r.y += q.y; r.z += q.z; r.w += q.w;
    }
    // masked means: sum / max(2*count, 1), each weighted by 0.5 (KEY_W)
    float l1 = (r.x / fmaxf(r.y * 2.0f, 1.0f)) * 0.5f;
    float l2 = (r.z / fmaxf(r.w * 2.0f, 1.0f)) * 0.5f;
    out[0] = l1 + l2;
  }
}

extern "C" void kernel_launch(void* const* d_in, const int* in_sizes, int n_in,
                              void* d_out, int out_size, void* d_ws, size_t ws_size,
                              hipStream_t stream) {
  const float* pred_c = (const float*)d_in[0];   // pred_contours (256,128,2)
  const float* pred_o = (const float*)d_in[1];   // pred_offsets  (256,128,2)
  const float* gt_c   = (const float*)d_in[2];   // gt_contours   (256,128,2)
  const float* gt_k   = (const float*)d_in[3];   // gt_key_points (256,128,2)
  const int*   mask   = (const int*)d_in[4];     // gt_key_points_mask (256,128)
  float4* partial = (float4*)d_ws;               // 256 * 16 B = 4 KB scratch

  dm_partial_kernel<<<N_, 1024, 0, stream>>>(pred_c, pred_o, gt_c, gt_k, mask, partial);
  dm_final_kernel<<<1, 256, 0, stream>>>(partial, (float*)d_out);
}